// Round 2
// baseline (1076.864 us; speedup 1.0000x reference)
//
#include <hip/hip_runtime.h>

#define N_NODES 50000
#define N_EDGES 800000

// ---------- shared 32->64->128->32 MLP block (relative smem layout) ----------
constexpr int M_W0T = 0;        // [64][32] transposed
constexpr int M_B0  = 2048;     // 64
constexpr int M_W1T = 2112;     // [128][64] transposed
constexpr int M_B1  = 10304;    // 128
constexpr int M_W2  = 10432;    // [128][32] natural
constexpr int M_B2  = 14528;    // 32
constexpr int M_SZ  = 14560;    // floats

__device__ __forceinline__ void stage_mlp(float* sm,
    const float* __restrict__ W0, const float* __restrict__ b0,
    const float* __restrict__ W1, const float* __restrict__ b1,
    const float* __restrict__ W2, const float* __restrict__ b2,
    int tid, int nthr) {
  for (int t = tid; t < 2048; t += nthr) {
    int j = t >> 5, k = t & 31;
    sm[M_W0T + t] = W0[k * 64 + j];          // W0 is [32][64]
  }
  for (int t = tid; t < 8192; t += nthr) {
    int k2 = t >> 6, j = t & 63;
    sm[M_W1T + t] = W1[j * 128 + k2];        // W1 is [64][128]
  }
  for (int t = tid; t < 4096; t += nthr) sm[M_W2 + t] = W2[t];
  for (int t = tid; t < 64; t += nthr)  sm[M_B0 + t] = b0[t];
  for (int t = tid; t < 128; t += nthr) sm[M_B1 + t] = b1[t];
  for (int t = tid; t < 32; t += nthr)  sm[M_B2 + t] = b2[t];
}

// full 4-input MLP core (used only in node kernel for pen path)
__device__ __forceinline__ void mlp_core(const float* sm, const float den[32],
                                         float h2[32]) {
  float h0[64];
#pragma unroll
  for (int j = 0; j < 64; ++j) {
    float a = sm[M_B0 + j];
#pragma unroll
    for (int k = 0; k < 32; ++k) a += den[k] * sm[M_W0T + j * 32 + k];
    h0[j] = fmaxf(a, 0.f);
  }
#pragma unroll
  for (int j = 0; j < 32; ++j) h2[j] = sm[M_B2 + j];
  for (int k2 = 0; k2 < 128; ++k2) {
    float t = sm[M_B1 + k2];
#pragma unroll
    for (int j = 0; j < 64; ++j) t += h0[j] * sm[M_W1T + k2 * 64 + j];
    t = fmaxf(t, 0.f);
#pragma unroll
    for (int j = 0; j < 32; ++j) h2[j] += t * sm[M_W2 + k2 * 32 + j];
  }
#pragma unroll
  for (int j = 0; j < 32; ++j) h2[j] = fmaxf(h2[j], 0.f);
}

// ------------------------------- CSR build ----------------------------------
__global__ void __launch_bounds__(256) count_kernel(const int* __restrict__ dst,
                                                    int* __restrict__ counts) {
  int e = blockIdx.x * 256 + threadIdx.x;
  if (e < N_EDGES) atomicAdd(&counts[dst[e]], 1);
}

__global__ void __launch_bounds__(1024) scan_kernel(int* __restrict__ counts,
                                                    int* __restrict__ offsets) {
  __shared__ int ps[1024];
  const int PER = (N_NODES + 1023) / 1024;  // 49
  int tid = threadIdx.x;
  int base = tid * PER;
  int s = 0;
  for (int i = 0; i < PER; ++i) {
    int idx = base + i;
    if (idx < N_NODES) s += counts[idx];
  }
  ps[tid] = s;
  __syncthreads();
  for (int off = 1; off < 1024; off <<= 1) {
    int t = (tid >= off) ? ps[tid - off] : 0;
    __syncthreads();
    ps[tid] += t;
    __syncthreads();
  }
  int run = ps[tid] - s;
  for (int i = 0; i < PER; ++i) {
    int idx = base + i;
    if (idx < N_NODES) {
      int c = counts[idx];
      offsets[idx] = run;
      counts[idx] = run;  // cursor for scatter
      run += c;
    }
  }
  if (tid == 1023) offsets[N_NODES] = ps[1023];
}

__global__ void __launch_bounds__(256) scatter_kernel(
    const int* __restrict__ src, const int* __restrict__ dst,
    int* __restrict__ cursor, int* __restrict__ csr_src,
    int* __restrict__ csr_dst) {
  int e = blockIdx.x * 256 + threadIdx.x;
  if (e >= N_EDGES) return;
  int d = dst[e];
  int slot = atomicAdd(&cursor[d], 1);
  csr_src[slot] = src[e];
  csr_dst[slot] = d;
}

// ------------------------------ node kernel ---------------------------------
// out[n][0:64]  = a[n]   = x@thW + thB
// gp[n][0:64]   = g[n]   = x@phW + phB - x@thW
// gp[n][64:128] = pen[n] = full 4-layer pen MLP(en[n])
// u[n][0:64]    = en @ tW0   (theta-MLP layer-0 partial, no bias/relu)
constexpr int NK_THT = 0;        // 2048
constexpr int NK_PHT = 2048;     // 2048
constexpr int NK_TW0 = 4096;     // 2048 (theta-MLP W0 transposed)
constexpr int NK_THB = 6144;     // 64
constexpr int NK_PHB = 6208;     // 64
constexpr int NK_B3  = 6272;     // 64
constexpr int NK_MLP = 6336;     // 14560 (pen MLP)
constexpr int NK_W3T = 20896;    // 2048 (pen W3 transposed)
constexpr int NK_SZ  = 22944;    // 91.8 KB

__global__ void __launch_bounds__(512) node_kernel(
    const float* __restrict__ x, const float* __restrict__ en,
    const float* __restrict__ thW, const float* __restrict__ thB,
    const float* __restrict__ phW, const float* __restrict__ phB,
    const float* __restrict__ tW0,
    const float* __restrict__ pW0, const float* __restrict__ pb0,
    const float* __restrict__ pW1, const float* __restrict__ pb1,
    const float* __restrict__ pW2, const float* __restrict__ pb2,
    const float* __restrict__ pW3, const float* __restrict__ pb3,
    float* __restrict__ out, float* __restrict__ gp, float* __restrict__ u) {
  __shared__ __align__(16) float sm[NK_SZ];
  const int tid = threadIdx.x;
  for (int t = tid; t < 2048; t += 512) {
    int j = t >> 5, k = t & 31;
    sm[NK_THT + t] = thW[k * 64 + j];
    sm[NK_PHT + t] = phW[k * 64 + j];
    sm[NK_TW0 + t] = tW0[k * 64 + j];
    sm[NK_W3T + t] = pW3[k * 64 + j];
  }
  for (int t = tid; t < 64; t += 512) {
    sm[NK_THB + t] = thB[t];
    sm[NK_PHB + t] = phB[t];
    sm[NK_B3 + t] = pb3[t];
  }
  stage_mlp(sm + NK_MLP, pW0, pb0, pW1, pb1, pW2, pb2, tid, 512);
  __syncthreads();
  int n = blockIdx.x * 512 + tid;
  if (n >= N_NODES) return;

  float xv[32];
  {
    const float4* p = (const float4*)(x + (long)n * 32);
#pragma unroll
    for (int q = 0; q < 8; ++q) {
      float4 v = p[q];
      xv[q * 4 + 0] = v.x; xv[q * 4 + 1] = v.y;
      xv[q * 4 + 2] = v.z; xv[q * 4 + 3] = v.w;
    }
  }
  float* ao = out + (long)n * 128;
  float* go = gp + (long)n * 128;
  for (int j = 0; j < 64; ++j) {
    float dth = 0.f, dph = 0.f;
#pragma unroll
    for (int k = 0; k < 32; ++k) {
      dth += xv[k] * sm[NK_THT + j * 32 + k];
      dph += xv[k] * sm[NK_PHT + j * 32 + k];
    }
    ao[j] = sm[NK_THB + j] + dth;          // a
    go[j] = sm[NK_PHB + j] + dph - dth;    // g
  }

  float ev[32];
  {
    const float4* p = (const float4*)(en + (long)n * 32);
#pragma unroll
    for (int q = 0; q < 8; ++q) {
      float4 v = p[q];
      ev[q * 4 + 0] = v.x; ev[q * 4 + 1] = v.y;
      ev[q * 4 + 2] = v.z; ev[q * 4 + 3] = v.w;
    }
  }
  // u[n] = en @ tW0 (no bias/relu)
  float* uo = u + (long)n * 64;
  for (int j = 0; j < 64; ++j) {
    float a = 0.f;
#pragma unroll
    for (int k = 0; k < 32; ++k) a += ev[k] * sm[NK_TW0 + j * 32 + k];
    uo[j] = a;
  }
  float h2p[32];
  mlp_core(sm + NK_MLP, ev, h2p);
  for (int j = 0; j < 64; ++j) {
    float o = sm[NK_B3 + j];
#pragma unroll
    for (int k = 0; k < 32; ++k) o += h2p[k] * sm[NK_W3T + j * 32 + k];
    go[64 + j] = o;                        // pen
  }
}

// ---------------- per-edge theta MLP (layers 1,2) + segmented sum -----------
constexpr int E_W1T = 0;        // [128][64]
constexpr int E_B1  = 8192;
constexpr int E_W2  = 8320;     // [128][32]
constexpr int E_B2  = 12416;
constexpr int E_B0  = 12448;
constexpr int E_SZ  = 12512;    // 50048 B

__device__ __forceinline__ void seg_reduce(int d, bool valid, float h2[32],
                                           float* __restrict__ h2sum) {
  int lane = threadIdx.x & 63;
  int dprev = __shfl_up(d, 1);
  bool head = (lane == 0) || (dprev != d);
  int seg = head ? lane : 0;
#pragma unroll
  for (int off = 1; off < 64; off <<= 1) {
    int t = __shfl_up(seg, off);
    if (lane >= off) seg = max(seg, t);
  }
#pragma unroll
  for (int off = 1; off < 64; off <<= 1) {
    bool take = (lane - off) >= seg;
#pragma unroll
    for (int k = 0; k < 32; ++k) {
      float t = __shfl_up(h2[k], off);
      h2[k] += take ? t : 0.f;
    }
  }
  int dnext = __shfl_down(d, 1);
  bool tail = (lane == 63) || (dnext != d);
  if (valid && tail) {
    float* hs = h2sum + (long)d * 32;
#pragma unroll
    for (int k = 0; k < 32; ++k) atomicAdd(&hs[k], h2[k]);
  }
}

__global__ void __launch_bounds__(256, 2) mlp_edge_kernel(
    const float* __restrict__ u,
    const int* __restrict__ csr_src, const int* __restrict__ csr_dst,
    const float* __restrict__ b0,
    const float* __restrict__ W1, const float* __restrict__ b1,
    const float* __restrict__ W2, const float* __restrict__ b2,
    float* __restrict__ h2sum) {
  __shared__ __align__(16) float sm[E_SZ];
  {
    const int tid = threadIdx.x;
    for (int t = tid; t < 8192; t += 256) {
      int k2 = t >> 6, j = t & 63;
      sm[E_W1T + t] = W1[j * 128 + k2];
    }
    for (int t = tid; t < 4096; t += 256) sm[E_W2 + t] = W2[t];
    for (int t = tid; t < 128; t += 256) sm[E_B1 + t] = b1[t];
    for (int t = tid; t < 64; t += 256) sm[E_B0 + t] = b0[t];
    for (int t = tid; t < 32; t += 256) sm[E_B2 + t] = b2[t];
  }
  __syncthreads();

  const long base = (long)blockIdx.x * 512;
  const int tid = threadIdx.x;
  // wave w handles two CONTIGUOUS 64-slot runs: [base+64w, +63] and
  // [base+256+64w, +63] -> segmented scan stays valid per run.
  const long sA = base + tid;
  const long sB = base + 256 + tid;
  const bool vA = sA < N_EDGES, vB = sB < N_EDGES;
  const int iA = vA ? (int)sA : 0, iB = vB ? (int)sB : 0;
  const int srcA = csr_src[iA], dA = csr_dst[iA];
  const int srcB = csr_src[iB], dB = csr_dst[iB];

  float h0a[64], h0b[64];
  {
    const float4* pd = (const float4*)(u + (long)dA * 64);
    const float4* ps = (const float4*)(u + (long)srcA * 64);
    const float4* qd = (const float4*)(u + (long)dB * 64);
    const float4* qs = (const float4*)(u + (long)srcB * 64);
#pragma unroll
    for (int q = 0; q < 16; ++q) {
      float4 a = pd[q], b = ps[q];
      h0a[q * 4 + 0] = a.x - b.x; h0a[q * 4 + 1] = a.y - b.y;
      h0a[q * 4 + 2] = a.z - b.z; h0a[q * 4 + 3] = a.w - b.w;
      float4 c = qd[q], e = qs[q];
      h0b[q * 4 + 0] = c.x - e.x; h0b[q * 4 + 1] = c.y - e.y;
      h0b[q * 4 + 2] = c.z - e.z; h0b[q * 4 + 3] = c.w - e.w;
    }
  }
#pragma unroll
  for (int j = 0; j < 64; ++j) {
    float bj = sm[E_B0 + j];
    h0a[j] = fmaxf(h0a[j] + bj, 0.f);
    h0b[j] = fmaxf(h0b[j] + bj, 0.f);
  }

  float h2a[32], h2b[32];
#pragma unroll
  for (int j = 0; j < 32; ++j) { float b2v = sm[E_B2 + j]; h2a[j] = b2v; h2b[j] = b2v; }
  for (int k2 = 0; k2 < 128; ++k2) {
    float ta = sm[E_B1 + k2], tb = ta;
#pragma unroll
    for (int j = 0; j < 64; ++j) {
      float w = sm[E_W1T + k2 * 64 + j];
      ta += h0a[j] * w; tb += h0b[j] * w;
    }
    ta = fmaxf(ta, 0.f); tb = fmaxf(tb, 0.f);
#pragma unroll
    for (int j = 0; j < 32; ++j) {
      float w = sm[E_W2 + k2 * 32 + j];
      h2a[j] += ta * w; h2b[j] += tb * w;
    }
  }
#pragma unroll
  for (int j = 0; j < 32; ++j) {
    h2a[j] = vA ? fmaxf(h2a[j], 0.f) : 0.f;
    h2b[j] = vB ? fmaxf(h2b[j], 0.f) : 0.f;
  }
  seg_reduce(vA ? dA : -1, vA, h2a, h2sum);
  seg_reduce(vB ? dB : -2, vB, h2b, h2sum);
}

// ------------------------- final gather / reduce -----------------------------
__global__ void __launch_bounds__(256) gather_kernel(
    const int* __restrict__ csr_src, const int* __restrict__ offsets,
    const float* __restrict__ gp, const float* __restrict__ h2sum,
    const float* __restrict__ tW3, const float* __restrict__ tb3,
    float* __restrict__ out) {
  __shared__ float sW3[2048 + 64];
  for (int t = threadIdx.x; t < 2048; t += 256) sW3[t] = tW3[t];
  for (int t = threadIdx.x; t < 64; t += 256) sW3[2048 + t] = tb3[t];
  __syncthreads();
  int n = blockIdx.x * 2 + (threadIdx.x >> 7);
  int j = threadIdx.x & 127;
  if (n >= N_NODES) return;
  int o0 = offsets[n], o1 = offsets[n + 1];
  int deg = o1 - o0;
  if (j < 64) {
    float m = -3.402823466e38f;
    for (int t = o0; t < o1; ++t) {
      int s = csr_src[t];
      m = fmaxf(m, gp[(long)s * 128 + j]);
    }
    float a = out[(long)n * 128 + j];
    out[(long)n * 128 + j] = (deg > 0) ? (a + m) : 0.f;
  } else {
    float ssum = 0.f;
    for (int t = o0; t < o1; ++t) {
      int s = csr_src[t];
      ssum += gp[(long)s * 128 + j];
    }
    int jj = j - 64;
    float w3 = 0.f;
    const float* h2r = h2sum + (long)n * 32;
#pragma unroll
    for (int k = 0; k < 32; ++k) w3 += h2r[k] * sW3[k * 64 + jj];
    float v = (ssum + w3 + (float)deg * sW3[2048 + jj]) / fmaxf((float)deg, 1.f);
    out[(long)n * 128 + j] = v;
  }
}

// ---------------------------------- launch -----------------------------------
extern "C" void kernel_launch(void* const* d_in, const int* in_sizes, int n_in,
                              void* d_out, int out_size, void* d_ws,
                              size_t ws_size, hipStream_t stream) {
  const float* x   = (const float*)d_in[0];
  const float* en  = (const float*)d_in[1];
  const int* src   = (const int*)d_in[2];
  const int* dst   = (const int*)d_in[3];
  const float* thW = (const float*)d_in[4];
  const float* thB = (const float*)d_in[5];
  const float* phW = (const float*)d_in[6];
  const float* phB = (const float*)d_in[7];
  const float* tW0 = (const float*)d_in[8];
  const float* tb0 = (const float*)d_in[9];
  const float* tW1 = (const float*)d_in[10];
  const float* tb1 = (const float*)d_in[11];
  const float* tW2 = (const float*)d_in[12];
  const float* tb2 = (const float*)d_in[13];
  const float* tW3 = (const float*)d_in[14];
  const float* tb3 = (const float*)d_in[15];
  const float* pW0 = (const float*)d_in[16];
  const float* pb0 = (const float*)d_in[17];
  const float* pW1 = (const float*)d_in[18];
  const float* pb1 = (const float*)d_in[19];
  const float* pW2 = (const float*)d_in[20];
  const float* pb2 = (const float*)d_in[21];
  const float* pW3 = (const float*)d_in[22];
  const float* pb3 = (const float*)d_in[23];

  float* out = (float*)d_out;
  float* ws  = (float*)d_ws;
  // ws layout (floats): gp[N*128], u[N*64], h2sum[N*32], then ints
  float* gp     = ws;                           // 6,400,000
  float* u      = ws + (long)N_NODES * 128;     // 3,200,000
  float* h2sum  = ws + (long)N_NODES * 192;     // 1,600,000
  int* iw       = (int*)(ws + (long)N_NODES * 224);
  int* csr_src  = iw;                           // E
  int* csr_dst  = iw + N_EDGES;                 // E
  int* counts   = iw + 2 * N_EDGES;             // N (becomes cursor)
  int* offsets  = counts + N_NODES;             // N+1
  // total ws ≈ (11.2M + 1.65M) * 4 B ≈ 51.5 MB

  hipMemsetAsync(counts, 0, N_NODES * sizeof(int), stream);
  hipMemsetAsync(h2sum, 0, (size_t)N_NODES * 32 * sizeof(float), stream);
  count_kernel<<<(N_EDGES + 255) / 256, 256, 0, stream>>>(dst, counts);
  scan_kernel<<<1, 1024, 0, stream>>>(counts, offsets);
  scatter_kernel<<<(N_EDGES + 255) / 256, 256, 0, stream>>>(
      src, dst, counts, csr_src, csr_dst);
  node_kernel<<<(N_NODES + 511) / 512, 512, 0, stream>>>(
      x, en, thW, thB, phW, phB, tW0, pW0, pb0, pW1, pb1, pW2, pb2, pW3, pb3,
      out, gp, u);
  mlp_edge_kernel<<<(N_EDGES + 511) / 512, 256, 0, stream>>>(
      u, csr_src, csr_dst, tb0, tW1, tb1, tW2, tb2, h2sum);
  gather_kernel<<<(N_NODES + 1) / 2, 256, 0, stream>>>(
      csr_src, offsets, gp, h2sum, tW3, tb3, out);
}

// Round 3
// 1011.861 us; speedup vs baseline: 1.0642x; 1.0642x over previous
//
#include <hip/hip_runtime.h>

#define N_NODES 50000
#define N_EDGES 800000

// ---------- shared 32->64->128->32 MLP block (relative smem layout) ----------
// (used only by node_kernel for the pen path)
constexpr int M_W0T = 0;        // [64][32] transposed
constexpr int M_B0  = 2048;     // 64
constexpr int M_W1T = 2112;     // [128][64] transposed
constexpr int M_B1  = 10304;    // 128
constexpr int M_W2  = 10432;    // [128][32] natural
constexpr int M_B2  = 14528;    // 32
constexpr int M_SZ  = 14560;    // floats

__device__ __forceinline__ void stage_mlp(float* sm,
    const float* __restrict__ W0, const float* __restrict__ b0,
    const float* __restrict__ W1, const float* __restrict__ b1,
    const float* __restrict__ W2, const float* __restrict__ b2,
    int tid, int nthr) {
  for (int t = tid; t < 2048; t += nthr) {
    int j = t >> 5, k = t & 31;
    sm[M_W0T + t] = W0[k * 64 + j];          // W0 is [32][64]
  }
  for (int t = tid; t < 8192; t += nthr) {
    int k2 = t >> 6, j = t & 63;
    sm[M_W1T + t] = W1[j * 128 + k2];        // W1 is [64][128]
  }
  for (int t = tid; t < 4096; t += nthr) sm[M_W2 + t] = W2[t];
  for (int t = tid; t < 64; t += nthr)  sm[M_B0 + t] = b0[t];
  for (int t = tid; t < 128; t += nthr) sm[M_B1 + t] = b1[t];
  for (int t = tid; t < 32; t += nthr)  sm[M_B2 + t] = b2[t];
}

__device__ __forceinline__ void mlp_core(const float* sm, const float den[32],
                                         float h2[32]) {
  float h0[64];
#pragma unroll
  for (int j = 0; j < 64; ++j) {
    float a = sm[M_B0 + j];
#pragma unroll
    for (int k = 0; k < 32; ++k) a += den[k] * sm[M_W0T + j * 32 + k];
    h0[j] = fmaxf(a, 0.f);
  }
#pragma unroll
  for (int j = 0; j < 32; ++j) h2[j] = sm[M_B2 + j];
  for (int k2 = 0; k2 < 128; ++k2) {
    float t = sm[M_B1 + k2];
#pragma unroll
    for (int j = 0; j < 64; ++j) t += h0[j] * sm[M_W1T + k2 * 64 + j];
    t = fmaxf(t, 0.f);
#pragma unroll
    for (int j = 0; j < 32; ++j) h2[j] += t * sm[M_W2 + k2 * 32 + j];
  }
#pragma unroll
  for (int j = 0; j < 32; ++j) h2[j] = fmaxf(h2[j], 0.f);
}

// ------------------------------- CSR build ----------------------------------
__global__ void __launch_bounds__(256) count_kernel(const int* __restrict__ dst,
                                                    int* __restrict__ counts) {
  int e = blockIdx.x * 256 + threadIdx.x;
  if (e < N_EDGES) atomicAdd(&counts[dst[e]], 1);
}

__global__ void __launch_bounds__(1024) scan_kernel(int* __restrict__ counts,
                                                    int* __restrict__ offsets) {
  __shared__ int ps[1024];
  const int PER = (N_NODES + 1023) / 1024;  // 49
  int tid = threadIdx.x;
  int base = tid * PER;
  int s = 0;
  for (int i = 0; i < PER; ++i) {
    int idx = base + i;
    if (idx < N_NODES) s += counts[idx];
  }
  ps[tid] = s;
  __syncthreads();
  for (int off = 1; off < 1024; off <<= 1) {
    int t = (tid >= off) ? ps[tid - off] : 0;
    __syncthreads();
    ps[tid] += t;
    __syncthreads();
  }
  int run = ps[tid] - s;
  for (int i = 0; i < PER; ++i) {
    int idx = base + i;
    if (idx < N_NODES) {
      int c = counts[idx];
      offsets[idx] = run;
      counts[idx] = run;  // cursor for scatter
      run += c;
    }
  }
  if (tid == 1023) offsets[N_NODES] = ps[1023];
}

__global__ void __launch_bounds__(256) scatter_kernel(
    const int* __restrict__ src, const int* __restrict__ dst,
    int* __restrict__ cursor, int* __restrict__ csr_src,
    int* __restrict__ csr_dst) {
  int e = blockIdx.x * 256 + threadIdx.x;
  if (e >= N_EDGES) return;
  int d = dst[e];
  int slot = atomicAdd(&cursor[d], 1);
  csr_src[slot] = src[e];
  csr_dst[slot] = d;
}

// W1T[k2][j] = W1[j][k2]  (theta-MLP layer-1 weights, transposed to ws)
__global__ void __launch_bounds__(256) prep_kernel(
    const float* __restrict__ W1, float* __restrict__ W1T) {
  int t = blockIdx.x * 256 + threadIdx.x;
  if (t < 8192) {
    int k2 = t >> 6, j = t & 63;
    W1T[t] = W1[j * 128 + k2];
  }
}

// ------------------------------ node kernel ---------------------------------
// out[n][0:64]  = a[n]   = x@thW + thB
// gp[n][0:64]   = g[n]   = x@phW + phB - x@thW
// gp[n][64:128] = pen[n] = full 4-layer pen MLP(en[n])
// u[n][0:64]    = en @ tW0   (theta-MLP layer-0 partial, no bias/relu)
constexpr int NK_THT = 0;        // 2048
constexpr int NK_PHT = 2048;     // 2048
constexpr int NK_TW0 = 4096;     // 2048 (theta-MLP W0 transposed)
constexpr int NK_THB = 6144;     // 64
constexpr int NK_PHB = 6208;     // 64
constexpr int NK_B3  = 6272;     // 64
constexpr int NK_MLP = 6336;     // 14560 (pen MLP)
constexpr int NK_W3T = 20896;    // 2048 (pen W3 transposed)
constexpr int NK_SZ  = 22944;    // 91.8 KB

__global__ void __launch_bounds__(512) node_kernel(
    const float* __restrict__ x, const float* __restrict__ en,
    const float* __restrict__ thW, const float* __restrict__ thB,
    const float* __restrict__ phW, const float* __restrict__ phB,
    const float* __restrict__ tW0,
    const float* __restrict__ pW0, const float* __restrict__ pb0,
    const float* __restrict__ pW1, const float* __restrict__ pb1,
    const float* __restrict__ pW2, const float* __restrict__ pb2,
    const float* __restrict__ pW3, const float* __restrict__ pb3,
    float* __restrict__ out, float* __restrict__ gp, float* __restrict__ u) {
  __shared__ __align__(16) float sm[NK_SZ];
  const int tid = threadIdx.x;
  for (int t = tid; t < 2048; t += 512) {
    int j = t >> 5, k = t & 31;
    sm[NK_THT + t] = thW[k * 64 + j];
    sm[NK_PHT + t] = phW[k * 64 + j];
    sm[NK_TW0 + t] = tW0[k * 64 + j];
    sm[NK_W3T + t] = pW3[k * 64 + j];
  }
  for (int t = tid; t < 64; t += 512) {
    sm[NK_THB + t] = thB[t];
    sm[NK_PHB + t] = phB[t];
    sm[NK_B3 + t] = pb3[t];
  }
  stage_mlp(sm + NK_MLP, pW0, pb0, pW1, pb1, pW2, pb2, tid, 512);
  __syncthreads();
  int n = blockIdx.x * 512 + tid;
  if (n >= N_NODES) return;

  float xv[32];
  {
    const float4* p = (const float4*)(x + (long)n * 32);
#pragma unroll
    for (int q = 0; q < 8; ++q) {
      float4 v = p[q];
      xv[q * 4 + 0] = v.x; xv[q * 4 + 1] = v.y;
      xv[q * 4 + 2] = v.z; xv[q * 4 + 3] = v.w;
    }
  }
  float* ao = out + (long)n * 128;
  float* go = gp + (long)n * 128;
  for (int j = 0; j < 64; ++j) {
    float dth = 0.f, dph = 0.f;
#pragma unroll
    for (int k = 0; k < 32; ++k) {
      dth += xv[k] * sm[NK_THT + j * 32 + k];
      dph += xv[k] * sm[NK_PHT + j * 32 + k];
    }
    ao[j] = sm[NK_THB + j] + dth;          // a
    go[j] = sm[NK_PHB + j] + dph - dth;    // g
  }

  float ev[32];
  {
    const float4* p = (const float4*)(en + (long)n * 32);
#pragma unroll
    for (int q = 0; q < 8; ++q) {
      float4 v = p[q];
      ev[q * 4 + 0] = v.x; ev[q * 4 + 1] = v.y;
      ev[q * 4 + 2] = v.z; ev[q * 4 + 3] = v.w;
    }
  }
  // u[n] = en @ tW0 (no bias/relu)
  float* uo = u + (long)n * 64;
  for (int j = 0; j < 64; ++j) {
    float a = 0.f;
#pragma unroll
    for (int k = 0; k < 32; ++k) a += ev[k] * sm[NK_TW0 + j * 32 + k];
    uo[j] = a;
  }
  float h2p[32];
  mlp_core(sm + NK_MLP, ev, h2p);
  for (int j = 0; j < 64; ++j) {
    float o = sm[NK_B3 + j];
#pragma unroll
    for (int k = 0; k < 32; ++k) o += h2p[k] * sm[NK_W3T + j * 32 + k];
    go[64 + j] = o;                        // pen
  }
}

// -------- per-edge theta MLP (layers 1,2) — scalar (SGPR) weights ------------
__device__ __forceinline__ void seg_reduce(int d, bool valid, float h2[32],
                                           float* __restrict__ h2sum) {
  int lane = threadIdx.x & 63;
  int dprev = __shfl_up(d, 1);
  bool head = (lane == 0) || (dprev != d);
  int seg = head ? lane : 0;
#pragma unroll
  for (int off = 1; off < 64; off <<= 1) {
    int t = __shfl_up(seg, off);
    if (lane >= off) seg = max(seg, t);
  }
#pragma unroll
  for (int off = 1; off < 64; off <<= 1) {
    bool take = (lane - off) >= seg;
#pragma unroll
    for (int k = 0; k < 32; ++k) {
      float t = __shfl_up(h2[k], off);
      h2[k] += take ? t : 0.f;
    }
  }
  int dnext = __shfl_down(d, 1);
  bool tail = (lane == 63) || (dnext != d);
  if (valid && tail) {
    float* hs = h2sum + (long)d * 32;
#pragma unroll
    for (int k = 0; k < 32; ++k) atomicAdd(&hs[k], h2[k]);
  }
}

__global__ void __launch_bounds__(256) mlp_edge_kernel(
    const float* __restrict__ u,
    const int* __restrict__ csr_src, const int* __restrict__ csr_dst,
    const float* __restrict__ b0g,
    const float* __restrict__ W1T,   // [128][64] pre-transposed (in ws)
    const float* __restrict__ b1g,
    const float* __restrict__ W2,    // [128][32] natural
    const float* __restrict__ b2g,
    float* __restrict__ h2sum) {
  long slot = (long)blockIdx.x * 256 + threadIdx.x;
  const bool valid = slot < N_EDGES;
  const int idx = valid ? (int)slot : 0;
  const int s = csr_src[idx], d = csr_dst[idx];

  // h0 = relu(u[d] - u[s] + b0)   (b0 reads are wave-uniform -> SGPR)
  float h0[64];
  {
    const float4* ud4 = (const float4*)(u + (long)d * 64);
    const float4* us4 = (const float4*)(u + (long)s * 64);
#pragma unroll
    for (int q = 0; q < 16; ++q) {
      float4 a = ud4[q], b = us4[q];
      h0[q * 4 + 0] = fmaxf(a.x - b.x + b0g[q * 4 + 0], 0.f);
      h0[q * 4 + 1] = fmaxf(a.y - b.y + b0g[q * 4 + 1], 0.f);
      h0[q * 4 + 2] = fmaxf(a.z - b.z + b0g[q * 4 + 2], 0.f);
      h0[q * 4 + 3] = fmaxf(a.w - b.w + b0g[q * 4 + 3], 0.f);
    }
  }

  float h2[32];
#pragma unroll
  for (int c = 0; c < 32; ++c) h2[c] = b2g[c];

  // k2-outer: W1T row (256B) and W2 row (128B) are contiguous, wave-uniform
  // -> s_load_dwordx16 on the scalar pipe; zero LDS traffic.
#pragma unroll 2
  for (int k2 = 0; k2 < 128; ++k2) {
    const float* wr = W1T + k2 * 64;
    float t0 = b1g[k2], t1 = 0.f, t2 = 0.f, t3 = 0.f;
#pragma unroll
    for (int j = 0; j < 16; ++j) {
      t0 += h0[j]      * wr[j];
      t1 += h0[j + 16] * wr[j + 16];
      t2 += h0[j + 32] * wr[j + 32];
      t3 += h0[j + 48] * wr[j + 48];
    }
    float t = fmaxf((t0 + t1) + (t2 + t3), 0.f);
    const float* w2r = W2 + k2 * 32;
#pragma unroll
    for (int c = 0; c < 32; ++c) h2[c] += t * w2r[c];
  }

#pragma unroll
  for (int c = 0; c < 32; ++c) h2[c] = valid ? fmaxf(h2[c], 0.f) : 0.f;
  seg_reduce(valid ? d : -1, valid, h2, h2sum);
}

// ------------------------- final gather / reduce -----------------------------
__global__ void __launch_bounds__(256) gather_kernel(
    const int* __restrict__ csr_src, const int* __restrict__ offsets,
    const float* __restrict__ gp, const float* __restrict__ h2sum,
    const float* __restrict__ tW3, const float* __restrict__ tb3,
    float* __restrict__ out) {
  __shared__ float sW3[2048 + 64];
  for (int t = threadIdx.x; t < 2048; t += 256) sW3[t] = tW3[t];
  for (int t = threadIdx.x; t < 64; t += 256) sW3[2048 + t] = tb3[t];
  __syncthreads();
  int n = blockIdx.x * 2 + (threadIdx.x >> 7);
  int j = threadIdx.x & 127;
  if (n >= N_NODES) return;
  int o0 = offsets[n], o1 = offsets[n + 1];
  int deg = o1 - o0;
  if (j < 64) {
    float m = -3.402823466e38f;
    for (int t = o0; t < o1; ++t) {
      int s = csr_src[t];
      m = fmaxf(m, gp[(long)s * 128 + j]);
    }
    float a = out[(long)n * 128 + j];
    out[(long)n * 128 + j] = (deg > 0) ? (a + m) : 0.f;
  } else {
    float ssum = 0.f;
    for (int t = o0; t < o1; ++t) {
      int s = csr_src[t];
      ssum += gp[(long)s * 128 + j];
    }
    int jj = j - 64;
    float w3 = 0.f;
    const float* h2r = h2sum + (long)n * 32;
#pragma unroll
    for (int k = 0; k < 32; ++k) w3 += h2r[k] * sW3[k * 64 + jj];
    float v = (ssum + w3 + (float)deg * sW3[2048 + jj]) / fmaxf((float)deg, 1.f);
    out[(long)n * 128 + j] = v;
  }
}

// ---------------------------------- launch -----------------------------------
extern "C" void kernel_launch(void* const* d_in, const int* in_sizes, int n_in,
                              void* d_out, int out_size, void* d_ws,
                              size_t ws_size, hipStream_t stream) {
  const float* x   = (const float*)d_in[0];
  const float* en  = (const float*)d_in[1];
  const int* src   = (const int*)d_in[2];
  const int* dst   = (const int*)d_in[3];
  const float* thW = (const float*)d_in[4];
  const float* thB = (const float*)d_in[5];
  const float* phW = (const float*)d_in[6];
  const float* phB = (const float*)d_in[7];
  const float* tW0 = (const float*)d_in[8];
  const float* tb0 = (const float*)d_in[9];
  const float* tW1 = (const float*)d_in[10];
  const float* tb1 = (const float*)d_in[11];
  const float* tW2 = (const float*)d_in[12];
  const float* tb2 = (const float*)d_in[13];
  const float* tW3 = (const float*)d_in[14];
  const float* tb3 = (const float*)d_in[15];
  const float* pW0 = (const float*)d_in[16];
  const float* pb0 = (const float*)d_in[17];
  const float* pW1 = (const float*)d_in[18];
  const float* pb1 = (const float*)d_in[19];
  const float* pW2 = (const float*)d_in[20];
  const float* pb2 = (const float*)d_in[21];
  const float* pW3 = (const float*)d_in[22];
  const float* pb3 = (const float*)d_in[23];

  float* out = (float*)d_out;
  float* ws  = (float*)d_ws;
  // ws layout (floats): gp[N*128], u[N*64], h2sum[N*32], w1t[8192], then ints
  float* gp     = ws;                           // 6,400,000
  float* u      = ws + (long)N_NODES * 128;     // 3,200,000
  float* h2sum  = ws + (long)N_NODES * 192;     // 1,600,000
  float* w1t    = ws + (long)N_NODES * 224;     // 8,192
  int* iw       = (int*)(w1t + 8192);
  int* csr_src  = iw;                           // E
  int* csr_dst  = iw + N_EDGES;                 // E
  int* counts   = iw + 2 * N_EDGES;             // N (becomes cursor)
  int* offsets  = counts + N_NODES;             // N+1
  // total ws ≈ 51.5 MB

  hipMemsetAsync(counts, 0, N_NODES * sizeof(int), stream);
  hipMemsetAsync(h2sum, 0, (size_t)N_NODES * 32 * sizeof(float), stream);
  prep_kernel<<<32, 256, 0, stream>>>(tW1, w1t);
  count_kernel<<<(N_EDGES + 255) / 256, 256, 0, stream>>>(dst, counts);
  scan_kernel<<<1, 1024, 0, stream>>>(counts, offsets);
  scatter_kernel<<<(N_EDGES + 255) / 256, 256, 0, stream>>>(
      src, dst, counts, csr_src, csr_dst);
  node_kernel<<<(N_NODES + 511) / 512, 512, 0, stream>>>(
      x, en, thW, thB, phW, phB, tW0, pW0, pb0, pW1, pb1, pW2, pb2, pW3, pb3,
      out, gp, u);
  mlp_edge_kernel<<<(N_EDGES + 255) / 256, 256, 0, stream>>>(
      u, csr_src, csr_dst, tb0, w1t, tb1, tW2, tb2, h2sum);
  gather_kernel<<<(N_NODES + 1) / 2, 256, 0, stream>>>(
      csr_src, offsets, gp, h2sum, tW3, tb3, out);
}